// Round 5
// baseline (1863.235 us; speedup 1.0000x reference)
//
#include <hip/hip_runtime.h>
#include <hip/hip_bf16.h>
#include <math.h>

#define BB 4
#define NN 2304
#define CC 256
#define HS 48
#define HID 1024
#define ATTN_SCALE 0.17677669529663687f  // 32^-0.5

typedef unsigned short ushort_t;

static __device__ __forceinline__ float bf2f(unsigned short u) {
    union { unsigned int i; float f; } x;
    x.i = ((unsigned int)u) << 16;
    return x.f;
}

// dtype detect (kept for robustness; resolves to fp32 on this problem):
// g1 is all-ones. fp32 word0 = 0x3F800000; bf16 pair = 0x3F803F80.
static __device__ __forceinline__ int det_bf(const void* g1) {
    return (*(const unsigned int*)g1) != 0x3F800000u;
}

static __device__ __forceinline__ float loadS(const void* p, size_t i, int bf) {
    return bf ? bf2f(((const ushort_t*)p)[i]) : ((const float*)p)[i];
}

// ---------------- block reduction (256 threads = 4 waves) ----------------
static __device__ __forceinline__ float block_sum256(float v) {
    __shared__ float sh[4];
    v += __shfl_down(v, 32, 64);
    v += __shfl_down(v, 16, 64);
    v += __shfl_down(v, 8, 64);
    v += __shfl_down(v, 4, 64);
    v += __shfl_down(v, 2, 64);
    v += __shfl_down(v, 1, 64);
    const int lane = threadIdx.x & 63;
    const int wid = threadIdx.x >> 6;
    if (lane == 0) sh[wid] = v;
    __syncthreads();
    float r = sh[0] + sh[1] + sh[2] + sh[3];
    __syncthreads();
    return r;
}

// ---------------- LayerNorm -> fp32 ws ----------------
// SRCWS=1: src is fp32 ws buffer (row0 unused). SRCWS=0: src is flagged d_in,
// rows offset by row0.
template <int SRCWS>
__global__ __launch_bounds__(256) void ln_kernel(
    const void* __restrict__ src, const void* __restrict__ g1det,
    const void* __restrict__ gamma, const void* __restrict__ beta,
    float* __restrict__ outp, int row0)
{
    const int row = blockIdx.x;
    const int t = threadIdx.x;
    const int bf = det_bf(g1det);
    float v;
    if (SRCWS) v = ((const float*)src)[(size_t)row * CC + t];
    else       v = loadS(src, (size_t)(row0 + row) * CC + t, bf);
    const float mu = block_sum256(v) * (1.0f / CC);
    const float d = v - mu;
    const float var = block_sum256(d * d) * (1.0f / CC);
    const float r = rsqrtf(var + 1e-6f);
    outp[(size_t)row * CC + t] = d * r * loadS(gamma, t, bf) + loadS(beta, t, bf);
}

// ---------------- naive GEMM: out = act(A[M,K]@W[K,N] + bias) + resid --------
// One thread per output element; A row staged in LDS; W read coalesced.
// RESID: 0 none; 1 flagged d_in residual at rows row0+m; 2 fp32 ws residual.
// Output is ALWAYS fp32 (d_out is float* per the reference's output dtype).
template <bool GELU, int RESID>
__global__ __launch_bounds__(256) void gemm_naive(
    const float* __restrict__ A, const void* __restrict__ g1det,
    const void* __restrict__ W, const void* __restrict__ bias,
    const void* __restrict__ resid, float* __restrict__ outp,
    int M, int N, int K, int row0)
{
    __shared__ float Arow[1024];   // K <= 1024
    const int m = blockIdx.y;
    const int n = blockIdx.x * 256 + threadIdx.x;   // N is a multiple of 256
    const int bf = det_bf(g1det);

    for (int k = threadIdx.x; k < K; k += 256)
        Arow[k] = A[(size_t)m * K + k];
    __syncthreads();

    float acc = 0.0f;
    if (bf) {
        const ushort_t* Wu = (const ushort_t*)W;
        for (int k = 0; k < K; ++k)
            acc = fmaf(Arow[k], bf2f(Wu[(size_t)k * N + n]), acc);
    } else {
        const float* Wf = (const float*)W;
        for (int k = 0; k < K; ++k)
            acc = fmaf(Arow[k], Wf[(size_t)k * N + n], acc);
    }

    float v = acc + loadS(bias, n, bf);
    if (GELU) v = 0.5f * v * (1.0f + erff(v * 0.70710678118654752f));
    if (RESID == 1) v += loadS(resid, (size_t)(row0 + m) * N + n, bf);
    if (RESID == 2) v += ((const float*)resid)[(size_t)m * N + n];
    outp[(size_t)m * N + n] = v;
}

// ---------------- sparse spatial attention (radius 3 -> <=29 neighbors) -------
// exp(-1e9 - m) == 0 in fp32, so only in-radius keys contribute: identical to
// the reference softmax over the masked score row.
__device__ __constant__ int ATT_DY[29] = {
    -3, -2, -2, -2, -2, -2, -1, -1, -1, -1, -1, 0, 0, 0, 0,
    0, 0, 0, 1, 1, 1, 1, 1, 2, 2, 2, 2, 2, 3};
__device__ __constant__ int ATT_DX[29] = {
    0, -2, -1, 0, 1, 2, -2, -1, 0, 1, 2, -3, -2, -1, 0,
    1, 2, 3, -2, -1, 0, 1, 2, -2, -1, 0, 1, 2, 0};

__global__ __launch_bounds__(256) void attn_kernel(
    const float* __restrict__ q, const float* __restrict__ k,
    const float* __restrict__ v, float* __restrict__ out)
{
    const int qi = blockIdx.x;         // row in batch
    const int tid = threadIdx.x;       // channel = h*32 + d  (HD == 32)
    const int qy = qi / HS;
    const int qx = qi - qy * HS;
    const float qv = q[(size_t)qi * CC + tid] * ATTN_SCALE;

    float m = -1e30f, l = 0.0f, acc = 0.0f;
#pragma unroll
    for (int nIdx = 0; nIdx < 29; ++nIdx) {
        const int ny = qy + ATT_DY[nIdx];
        const int nx = qx + ATT_DX[nIdx];
        if ((unsigned)ny < HS && (unsigned)nx < HS) {  // block-uniform branch
            const int kj = ny * HS + nx;
            const size_t koff = (size_t)kj * CC + tid;
            float s = qv * k[koff];
            s += __shfl_xor(s, 16, 32);
            s += __shfl_xor(s, 8, 32);
            s += __shfl_xor(s, 4, 32);
            s += __shfl_xor(s, 2, 32);
            s += __shfl_xor(s, 1, 32);
            const float mn = fmaxf(m, s);
            const float c = expf(m - mn);
            const float p = expf(s - mn);
            l = l * c + p;
            acc = acc * c + p * v[koff];
            m = mn;
        }
    }
    out[(size_t)qi * CC + tid] = acc / l;
}

extern "C" void kernel_launch(void* const* d_in, const int* in_sizes, int n_in,
                              void* d_out, int out_size, void* d_ws, size_t ws_size,
                              hipStream_t stream) {
    const void* x    = d_in[0];
    const void* x_kv = d_in[1];
    const void* Wq   = d_in[2];
    const void* bq   = d_in[3];
    const void* Wk   = d_in[4];
    const void* bk   = d_in[5];
    const void* Wv   = d_in[6];
    const void* bv   = d_in[7];
    const void* Wp   = d_in[8];
    const void* bp   = d_in[9];
    const void* g1   = d_in[10];
    const void* b1   = d_in[11];
    const void* g2   = d_in[12];
    const void* b2   = d_in[13];
    const void* W1   = d_in[14];
    const void* bm1  = d_in[15];
    const void* W2   = d_in[16];
    const void* bm2  = d_in[17];
    float* outp = (float*)d_out;   // fp32 output per the reference's dtype

    // Per-batch fp32 buffers, NO overlays: 8 x RCf floats (18.9 MB) + hid.
    const size_t RCf = (size_t)NN * CC;    // 589824 floats
    float* ws  = (float*)d_ws;
    float* h   = ws + 0 * RCf;
    float* hkv = ws + 1 * RCf;
    float* qb  = ws + 2 * RCf;
    float* kb  = ws + 3 * RCf;
    float* vb  = ws + 4 * RCf;
    float* ao  = ws + 5 * RCf;
    float* x1  = ws + 6 * RCf;
    float* m2  = ws + 7 * RCf;
    const int RCHUNK = 576;
    float* hid;
    if (ws_size >= (8 * RCf + (size_t)RCHUNK * HID) * sizeof(float))
        hid = ws + 8 * RCf;
    else
        hid = ao;   // 576*1024 == RCf floats exactly; ao is dead by then

    const dim3 gP(CC / 256, NN);           // (1, 2304) projection GEMMs
    const dim3 gM1(HID / 256, RCHUNK);     // (4, 576)  MLP up chunk
    const dim3 gM2(CC / 256, RCHUNK);      // (1, 576)  MLP down chunk

    for (int b = 0; b < BB; ++b) {
        const int row0 = b * NN;
        float* ob = outp + (size_t)row0 * CC;

        // 1. LayerNorm of x[b] and x_kv[b] (shared g1, b1)
        ln_kernel<0><<<NN, 256, 0, stream>>>(x,    g1, g1, b1, h,   row0);
        ln_kernel<0><<<NN, 256, 0, stream>>>(x_kv, g1, g1, b1, hkv, row0);

        // 2. Q, K, V projections
        gemm_naive<false, 0><<<gP, 256, 0, stream>>>(
            h,   g1, Wq, bq, nullptr, qb, NN, CC, CC, 0);
        gemm_naive<false, 0><<<gP, 256, 0, stream>>>(
            hkv, g1, Wk, bk, nullptr, kb, NN, CC, CC, 0);
        gemm_naive<false, 0><<<gP, 256, 0, stream>>>(
            hkv, g1, Wv, bv, nullptr, vb, NN, CC, CC, 0);

        // 3. sparse local attention
        attn_kernel<<<NN, 256, 0, stream>>>(qb, kb, vb, ao);

        // 4. output projection + residual x[b]  -> x1 (fp32)
        gemm_naive<false, 1><<<gP, 256, 0, stream>>>(
            ao, g1, Wp, bp, x, x1, NN, CC, CC, row0);

        // 5. LayerNorm2 -> m2
        ln_kernel<1><<<NN, 256, 0, stream>>>(x1, g1, g2, b2, m2, 0);

        // 6/7. MLP in row chunks; final store fp32 DIRECTLY to d_out
        for (int c0 = 0; c0 < NN; c0 += RCHUNK) {
            const float* m2C = m2 + (size_t)c0 * CC;
            const float* x1C = x1 + (size_t)c0 * CC;
            float* obC = ob + (size_t)c0 * CC;
            gemm_naive<true, 0><<<gM1, 256, 0, stream>>>(
                m2C, g1, W1, bm1, nullptr, hid, RCHUNK, HID, CC, 0);
            gemm_naive<false, 2><<<gM2, 256, 0, stream>>>(
                hid, g1, W2, bm2, x1C, obC, RCHUNK, CC, HID, 0);
        }
    }
    (void)in_sizes; (void)n_in; (void)out_size;
}

// Round 6
// 419.297 us; speedup vs baseline: 4.4437x; 4.4437x over previous
//
#include <hip/hip_runtime.h>
#include <hip/hip_bf16.h>
#include <math.h>

#define BB 4
#define NN 2304
#define CC 256
#define HS 48
#define HID 1024
#define BNROWS (BB * NN)                 // 9216
#define ATTN_SCALE 0.17677669529663687f  // 32^-0.5

typedef unsigned short ushort_t;
typedef __attribute__((ext_vector_type(8))) short short8;   // 8 bf16 = 4 VGPRs
typedef __attribute__((ext_vector_type(4))) float float4v;  // MFMA acc

static __device__ __forceinline__ float bf2f(unsigned short u) {
    union { unsigned int i; float f; } x;
    x.i = ((unsigned int)u) << 16;
    return x.f;
}

static __device__ __forceinline__ unsigned short f2bf(float f) {
    union { float f; unsigned int i; } x;
    x.f = f;
    unsigned int r = x.i + 0x7FFFu + ((x.i >> 16) & 1u);  // RNE
    return (unsigned short)(r >> 16);
}

// ---------------- block reduction (256 threads = 4 waves) ----------------
static __device__ __forceinline__ float block_sum256(float v) {
    __shared__ float sh[4];
    v += __shfl_down(v, 32, 64);
    v += __shfl_down(v, 16, 64);
    v += __shfl_down(v, 8, 64);
    v += __shfl_down(v, 4, 64);
    v += __shfl_down(v, 2, 64);
    v += __shfl_down(v, 1, 64);
    const int lane = threadIdx.x & 63;
    const int wid = threadIdx.x >> 6;
    if (lane == 0) sh[wid] = v;
    __syncthreads();
    float r = sh[0] + sh[1] + sh[2] + sh[3];
    __syncthreads();
    return r;
}

// ---------------- LayerNorm (fp32 in) -> bf16 out ----------------
__global__ __launch_bounds__(256) void ln_dual_kernel(
    const float* __restrict__ x, const float* __restrict__ xkv,
    const float* __restrict__ g, const float* __restrict__ be,
    ushort_t* __restrict__ h, ushort_t* __restrict__ hkv)
{
    const int row = blockIdx.x;  // 0..2*BNROWS-1
    const float* src;
    ushort_t* dst;
    if (row < BNROWS) { src = x + (size_t)row * CC;            dst = h + (size_t)row * CC; }
    else              { src = xkv + (size_t)(row - BNROWS) * CC; dst = hkv + (size_t)(row - BNROWS) * CC; }
    const int t = threadIdx.x;
    const float v = src[t];
    const float mu = block_sum256(v) * (1.0f / CC);
    const float d = v - mu;
    const float var = block_sum256(d * d) * (1.0f / CC);
    const float r = rsqrtf(var + 1e-6f);
    dst[t] = f2bf(d * r * g[t] + be[t]);
}

__global__ __launch_bounds__(256) void ln_single_kernel(
    const float* __restrict__ src, const float* __restrict__ g,
    const float* __restrict__ be, ushort_t* __restrict__ dst)
{
    const int row = blockIdx.x;
    const int t = threadIdx.x;
    const float v = src[(size_t)row * CC + t];
    const float mu = block_sum256(v) * (1.0f / CC);
    const float d = v - mu;
    const float var = block_sum256(d * d) * (1.0f / CC);
    const float r = rsqrtf(var + 1e-6f);
    dst[(size_t)row * CC + t] = f2bf(d * r * g[t] + be[t]);
}

// ---------------- MFMA GEMM: out = act(A[M,K]@W[K,N] + bias) + resid ---------
// A: bf16 ws. W/bias: fp32 d_in (W converted to bf16 during LDS staging).
// Tile 64(M)x64(N), BK=32, 4 waves each owning a 64x16 N-strip.
// MFMA 16x16x32 bf16: A-op lane&15=m, (lane>>4)*8+j=k; B-op lane&15=n (via
// transposed LDS [n][k]); C/D row=(lane>>4)*4+r, col=lane&15.
template <bool GELU, bool RESID, bool OUTBF>
__global__ __launch_bounds__(256) void gemm_mfma(
    const ushort_t* __restrict__ A, const float* __restrict__ W,
    const float* __restrict__ bias, const float* __restrict__ resid,
    void* __restrict__ outp, int M, int N, int K)
{
    __shared__ ushort_t Asb[64][40];  // [m][k], pad 32->40 vs bank conflicts
    __shared__ ushort_t Bsb[64][40];  // [n][k] (transposed W tile)

    const int tid = threadIdx.x;
    const int wid = tid >> 6;
    const int lane = tid & 63;
    const int ln15 = lane & 15;
    const int quad = lane >> 4;
    const int m0 = blockIdx.y * 64;
    const int n0 = blockIdx.x * 64;

    const int arow = tid >> 2;          // 0..63
    const int achk = (tid & 3) * 8;     // 0,8,16,24
    const int bkr = tid >> 3;           // 0..31
    const int bng = (tid & 7) * 8;      // 0,8,..,56

    float4v acc[4];
#pragma unroll
    for (int i = 0; i < 4; ++i) acc[i] = (float4v){0.f, 0.f, 0.f, 0.f};

    for (int k0 = 0; k0 < K; k0 += 32) {
        // stage A tile (bf16, straight copy, 16 B per thread)
        const uint4 av = *reinterpret_cast<const uint4*>(
            A + (size_t)(m0 + arow) * K + k0 + achk);
        *reinterpret_cast<uint4*>(&Asb[arow][achk]) = av;
        // stage W tile fp32 -> bf16, transposed to [n][k]
        const float4 w0 = *reinterpret_cast<const float4*>(
            W + (size_t)(k0 + bkr) * N + n0 + bng);
        const float4 w1 = *reinterpret_cast<const float4*>(
            W + (size_t)(k0 + bkr) * N + n0 + bng + 4);
        Bsb[bng + 0][bkr] = f2bf(w0.x);
        Bsb[bng + 1][bkr] = f2bf(w0.y);
        Bsb[bng + 2][bkr] = f2bf(w0.z);
        Bsb[bng + 3][bkr] = f2bf(w0.w);
        Bsb[bng + 4][bkr] = f2bf(w1.x);
        Bsb[bng + 5][bkr] = f2bf(w1.y);
        Bsb[bng + 6][bkr] = f2bf(w1.z);
        Bsb[bng + 7][bkr] = f2bf(w1.w);
        __syncthreads();

        const short8 bF = *reinterpret_cast<const short8*>(
            &Bsb[wid * 16 + ln15][quad * 8]);
#pragma unroll
        for (int mt = 0; mt < 4; ++mt) {
            const short8 aF = *reinterpret_cast<const short8*>(
                &Asb[mt * 16 + ln15][quad * 8]);
            acc[mt] = __builtin_amdgcn_mfma_f32_16x16x32_bf16(aF, bF, acc[mt], 0, 0, 0);
        }
        __syncthreads();
    }

    const int gn = n0 + wid * 16 + ln15;
    const float bsv = bias[gn];
#pragma unroll
    for (int mt = 0; mt < 4; ++mt) {
#pragma unroll
        for (int r = 0; r < 4; ++r) {
            const int gm = m0 + mt * 16 + quad * 4 + r;
            float v = acc[mt][r] + bsv;
            if (GELU) v = 0.5f * v * (1.0f + erff(v * 0.70710678118654752f));
            if (RESID) v += resid[(size_t)gm * N + gn];
            if (OUTBF) ((ushort_t*)outp)[(size_t)gm * N + gn] = f2bf(v);
            else ((float*)outp)[(size_t)gm * N + gn] = v;
        }
    }
}

// ---------------- sparse spatial attention (radius 3 -> <=29 neighbors) ------
// exp(-1e9 - m) == 0 in fp32, so only in-radius keys contribute: identical
// to the reference softmax over the masked score row.
__device__ __constant__ int ATT_DY[29] = {
    -3, -2, -2, -2, -2, -2, -1, -1, -1, -1, -1, 0, 0, 0, 0,
    0, 0, 0, 1, 1, 1, 1, 1, 2, 2, 2, 2, 2, 3};
__device__ __constant__ int ATT_DX[29] = {
    0, -2, -1, 0, 1, 2, -2, -1, 0, 1, 2, -3, -2, -1, 0,
    1, 2, 3, -2, -1, 0, 1, 2, -2, -1, 0, 1, 2, 0};

__global__ __launch_bounds__(256) void attn_kernel(
    const ushort_t* __restrict__ q, const ushort_t* __restrict__ k,
    const ushort_t* __restrict__ v, ushort_t* __restrict__ out)
{
    const int gq = blockIdx.x;          // 0..BNROWS-1
    const int b = gq / NN;
    const int qi = gq - b * NN;
    const int tid = threadIdx.x;        // channel = h*32 + d (HD == 32)
    const int qy = qi / HS;
    const int qx = qi - qy * HS;
    const size_t base = (size_t)b * NN * CC;
    const float qv = bf2f(q[base + (size_t)qi * CC + tid]) * ATTN_SCALE;

    float m = -1e30f, l = 0.0f, acc = 0.0f;
#pragma unroll
    for (int nIdx = 0; nIdx < 29; ++nIdx) {
        const int ny = qy + ATT_DY[nIdx];
        const int nx = qx + ATT_DX[nIdx];
        if ((unsigned)ny < HS && (unsigned)nx < HS) {  // block-uniform branch
            const int kj = ny * HS + nx;
            const size_t koff = base + (size_t)kj * CC + tid;
            float s = qv * bf2f(k[koff]);
            s += __shfl_xor(s, 16, 32);
            s += __shfl_xor(s, 8, 32);
            s += __shfl_xor(s, 4, 32);
            s += __shfl_xor(s, 2, 32);
            s += __shfl_xor(s, 1, 32);
            const float mn = fmaxf(m, s);
            const float c = expf(m - mn);
            const float p = expf(s - mn);
            l = l * c + p;
            acc = acc * c + p * bf2f(v[koff]);
            m = mn;
        }
    }
    out[base + (size_t)qi * CC + tid] = f2bf(acc / l);
}

extern "C" void kernel_launch(void* const* d_in, const int* in_sizes, int n_in,
                              void* d_out, int out_size, void* d_ws, size_t ws_size,
                              hipStream_t stream) {
    const float* x    = (const float*)d_in[0];
    const float* x_kv = (const float*)d_in[1];
    const float* Wq   = (const float*)d_in[2];
    const float* bq   = (const float*)d_in[3];
    const float* Wk   = (const float*)d_in[4];
    const float* bk   = (const float*)d_in[5];
    const float* Wv   = (const float*)d_in[6];
    const float* bv   = (const float*)d_in[7];
    const float* Wp   = (const float*)d_in[8];
    const float* bp   = (const float*)d_in[9];
    const float* g1   = (const float*)d_in[10];
    const float* b1   = (const float*)d_in[11];
    const float* g2   = (const float*)d_in[12];
    const float* b2   = (const float*)d_in[13];
    const float* W1   = (const float*)d_in[14];
    const float* bm1  = (const float*)d_in[15];
    const float* W2   = (const float*)d_in[16];
    const float* bm2  = (const float*)d_in[17];
    float* outp = (float*)d_out;   // fp32 output (verified round 5)

    // ws: 4 bf16 slots of RC = BNROWS*CC elements; peak 18.87 MB (same
    // footprint as the validated round-4 layout). Slot lifetimes:
    //   s0: hq   -> vb   -> m2
    //   s1: hkv  -> ao   -> hid (per batch, 2304*1024 == RC exactly)
    //   s2: qb  --+
    //   s3: kb  --+--> x1 (fp32, RC floats spans s2+s3)
    const size_t RC = (size_t)BNROWS * CC;  // 2359296
    ushort_t* s0 = (ushort_t*)d_ws;
    ushort_t* hq  = s0;
    ushort_t* hkv = s0 + RC;
    ushort_t* qb  = s0 + 2 * RC;
    ushort_t* kb  = s0 + 3 * RC;
    ushort_t* vb  = hq;
    ushort_t* ao  = hkv;
    float*    x1  = (float*)(s0 + 2 * RC);
    ushort_t* m2  = hq;
    ushort_t* hid = hkv;

    const dim3 gP(CC / 64, BNROWS / 64);   // (4, 144) QKV/proj
    const dim3 gU(HID / 64, NN / 64);      // (16, 36) MLP up, per batch
    const dim3 gD(CC / 64, NN / 64);       // (4, 36)  MLP down, per batch

    // 1. LN of x and x_kv (one fused launch)
    ln_dual_kernel<<<2 * BNROWS, 256, 0, stream>>>(x, x_kv, g1, b1, hq, hkv);

    // 2. QKV projections (full batch, M = 9216)
    gemm_mfma<false, false, true><<<gP, 256, 0, stream>>>(
        hq, Wq, bq, nullptr, qb, BNROWS, CC, CC);
    gemm_mfma<false, false, true><<<gP, 256, 0, stream>>>(
        hkv, Wk, bk, nullptr, kb, BNROWS, CC, CC);
    gemm_mfma<false, false, true><<<gP, 256, 0, stream>>>(
        hkv, Wv, bv, nullptr, vb, BNROWS, CC, CC);

    // 3. sparse local attention
    attn_kernel<<<BNROWS, 256, 0, stream>>>(qb, kb, vb, ao);

    // 4. out-projection + residual x -> x1 (fp32)
    gemm_mfma<false, true, false><<<gP, 256, 0, stream>>>(
        ao, Wp, bp, x, x1, BNROWS, CC, CC);

    // 5. LN2 -> m2 (bf16)
    ln_single_kernel<<<BNROWS, 256, 0, stream>>>(x1, g2, b2, m2);

    // 6/7. MLP per batch (hid slot reused; stream order serializes)
    for (int b = 0; b < BB; ++b) {
        const ushort_t* m2b = m2 + (size_t)b * NN * CC;
        const float* x1b = x1 + (size_t)b * NN * CC;
        float* ob = outp + (size_t)b * NN * CC;
        gemm_mfma<true, false, true><<<gU, 256, 0, stream>>>(
            m2b, W1, bm1, nullptr, hid, NN, HID, CC);
        gemm_mfma<false, true, false><<<gD, 256, 0, stream>>>(
            hid, W2, bm2, x1b, ob, NN, CC, HID);
    }
    (void)in_sizes; (void)n_in; (void)out_size; (void)ws_size;
}

// Round 7
// 210.704 us; speedup vs baseline: 8.8429x; 1.9900x over previous
//
#include <hip/hip_runtime.h>
#include <hip/hip_fp16.h>
#include <math.h>

#define BB 4
#define NN 2304
#define CC 256
#define HS 48
#define HID 1024
#define BNROWS (BB * NN)                 // 9216
#define ATTN_SCALE 0.17677669529663687f  // 32^-0.5

typedef _Float16 f16;
typedef __attribute__((ext_vector_type(2))) _Float16 h2;
typedef __attribute__((ext_vector_type(8))) _Float16 h8;
typedef __attribute__((ext_vector_type(4))) float f4;

// ---------------- block reduction (256 threads = 4 waves) ----------------
static __device__ __forceinline__ float block_sum256(float v) {
    __shared__ float sh[4];
    v += __shfl_down(v, 32, 64);
    v += __shfl_down(v, 16, 64);
    v += __shfl_down(v, 8, 64);
    v += __shfl_down(v, 4, 64);
    v += __shfl_down(v, 2, 64);
    v += __shfl_down(v, 1, 64);
    const int lane = threadIdx.x & 63;
    const int wid = threadIdx.x >> 6;
    if (lane == 0) sh[wid] = v;
    __syncthreads();
    float r = sh[0] + sh[1] + sh[2] + sh[3];
    __syncthreads();
    return r;
}

// ---------------- weight prep: fp32 [K][N] -> f16 [N][K] (transposed) --------
// 32x32 LDS tile transpose; one kernel covers all 6 matrices (768 tiles).
__global__ __launch_bounds__(256) void prep_kernel(
    const float* __restrict__ Wq, const float* __restrict__ Wk,
    const float* __restrict__ Wv, const float* __restrict__ Wp,
    const float* __restrict__ W1, const float* __restrict__ W2,
    f16* __restrict__ WqT, f16* __restrict__ WkvT, f16* __restrict__ WpT,
    f16* __restrict__ W1T, f16* __restrict__ W2T)
{
    __shared__ float t[32][33];
    int bx = blockIdx.x;
    const float* src; f16* dst; int K, N;
    if (bx < 64)        { src = Wq; dst = WqT;               K = 256;  N = 256; }
    else if (bx < 128)  { src = Wk; dst = WkvT;              K = 256;  N = 256;  bx -= 64; }
    else if (bx < 192)  { src = Wv; dst = WkvT + 256 * 256;  K = 256;  N = 256;  bx -= 128; }
    else if (bx < 256)  { src = Wp; dst = WpT;               K = 256;  N = 256;  bx -= 192; }
    else if (bx < 512)  { src = W1; dst = W1T;               K = 256;  N = 1024; bx -= 256; }
    else                { src = W2; dst = W2T;               K = 1024; N = 256;  bx -= 512; }
    const int tN = N >> 5;
    const int kt = bx / tN, nt = bx - kt * tN;
    const int rr = threadIdx.x >> 5, cc = threadIdx.x & 31;
#pragma unroll
    for (int j = 0; j < 4; ++j)
        t[rr + 8 * j][cc] = src[(size_t)(kt * 32 + rr + 8 * j) * N + nt * 32 + cc];
    __syncthreads();
#pragma unroll
    for (int j = 0; j < 4; ++j)
        dst[(size_t)(nt * 32 + rr + 8 * j) * K + kt * 32 + cc] = (f16)t[cc][rr + 8 * j];
}

// ---------------- LayerNorm fp32 -> f16 ----------------
__global__ __launch_bounds__(256) void ln_dual_kernel(
    const float* __restrict__ x, const float* __restrict__ xkv,
    const float* __restrict__ g, const float* __restrict__ be,
    f16* __restrict__ h, f16* __restrict__ hkv)
{
    const int row = blockIdx.x;  // 0..2*BNROWS-1
    const float* src;
    f16* dst;
    if (row < BNROWS) { src = x + (size_t)row * CC;              dst = h + (size_t)row * CC; }
    else              { src = xkv + (size_t)(row - BNROWS) * CC; dst = hkv + (size_t)(row - BNROWS) * CC; }
    const int t = threadIdx.x;
    const float v = src[t];
    const float mu = block_sum256(v) * (1.0f / CC);
    const float d = v - mu;
    const float var = block_sum256(d * d) * (1.0f / CC);
    const float r = rsqrtf(var + 1e-6f);
    dst[t] = (f16)(d * r * g[t] + be[t]);
}

__global__ __launch_bounds__(256) void ln_single_kernel(
    const float* __restrict__ src, const float* __restrict__ g,
    const float* __restrict__ be, f16* __restrict__ dst)
{
    const int row = blockIdx.x;
    const int t = threadIdx.x;
    const float v = src[(size_t)row * CC + t];
    const float mu = block_sum256(v) * (1.0f / CC);
    const float d = v - mu;
    const float var = block_sum256(d * d) * (1.0f / CC);
    const float r = rsqrtf(var + 1e-6f);
    dst[(size_t)row * CC + t] = (f16)(d * r * g[t] + be[t]);
}

// ---------------- MFMA f16 GEMM: out = act(A[M,K]@Bt^T + bias) + resid -------
// A f16 [M][K]; Bt f16 [N][K] (pre-transposed weights). Tile 128(M)x64(N),
// BK=32, 4 waves; wave owns 32(M)x64(N) -> 2x4 MFMA 16x16x32 per K-step.
// DUALB: bias = n<256 ? bias[n] : bias2[n-256] (fused K|V).
template <bool GELU, int RESID, int OUTF32, bool DUALB>
__global__ __launch_bounds__(256) void gemm_f16(
    const f16* __restrict__ A, const f16* __restrict__ Bt,
    const float* __restrict__ bias, const float* __restrict__ bias2,
    const float* __restrict__ resid, void* __restrict__ outp,
    int M, int N, int K)
{
    __shared__ f16 As[128][40];   // pad 32->40: 2-way max on frag reads
    __shared__ f16 Bs[64][40];
    const int tid = threadIdx.x;
    const int wid = tid >> 6, lane = tid & 63;
    const int ln15 = lane & 15, quad = lane >> 4;
    const int m0 = blockIdx.y * 128, n0 = blockIdx.x * 64;

    const int ar0 = tid >> 2, ak0 = (tid & 3) << 3;          // A: idx=tid
    const int ar1 = (tid + 256) >> 2, ak1 = ak0;             // A: idx=tid+256
    const int bn = tid >> 2, bk = (tid & 3) << 3;            // B

    f4 acc[2][4];
#pragma unroll
    for (int i = 0; i < 2; ++i)
#pragma unroll
        for (int j = 0; j < 4; ++j) acc[i][j] = (f4){0.f, 0.f, 0.f, 0.f};

    for (int k0 = 0; k0 < K; k0 += 32) {
        *(uint4*)&As[ar0][ak0] = *(const uint4*)&A[(size_t)(m0 + ar0) * K + k0 + ak0];
        *(uint4*)&As[ar1][ak1] = *(const uint4*)&A[(size_t)(m0 + ar1) * K + k0 + ak1];
        *(uint4*)&Bs[bn][bk]   = *(const uint4*)&Bt[(size_t)(n0 + bn) * K + k0 + bk];
        __syncthreads();
        h8 bF[4], aF[2];
#pragma unroll
        for (int nt = 0; nt < 4; ++nt)
            bF[nt] = *(const h8*)&Bs[nt * 16 + ln15][quad * 8];
#pragma unroll
        for (int mt = 0; mt < 2; ++mt)
            aF[mt] = *(const h8*)&As[wid * 32 + mt * 16 + ln15][quad * 8];
#pragma unroll
        for (int mt = 0; mt < 2; ++mt)
#pragma unroll
            for (int nt = 0; nt < 4; ++nt)
                acc[mt][nt] = __builtin_amdgcn_mfma_f32_16x16x32_f16(
                    aF[mt], bF[nt], acc[mt][nt], 0, 0, 0);
        __syncthreads();
    }

#pragma unroll
    for (int nt = 0; nt < 4; ++nt) {
        const int gn = n0 + nt * 16 + ln15;
        const float bs = DUALB ? (gn < 256 ? bias[gn] : bias2[gn - 256]) : bias[gn];
#pragma unroll
        for (int mt = 0; mt < 2; ++mt) {
#pragma unroll
            for (int r = 0; r < 4; ++r) {
                const int gm = m0 + wid * 32 + mt * 16 + quad * 4 + r;
                float v = acc[mt][nt][r] + bs;
                if (GELU) v = 0.5f * v * (1.0f + erff(v * 0.70710678118654752f));
                if (RESID) v += resid[(size_t)gm * N + gn];
                if (OUTF32) ((float*)outp)[(size_t)gm * N + gn] = v;
                else ((f16*)outp)[(size_t)gm * N + gn] = (f16)v;
            }
        }
    }
}

// ---------------- tiled sparse spatial attention ----------------
// Block = (8x8 query tile, head-pair, batch); 128 threads = (64 q) x (2 heads).
// K/V neighborhood (14x14 rows x 64 ch) staged in LDS f16. Two-pass softmax:
// exp(-1e9-m)==0 in fp32 so only in-radius keys contribute (== reference).
__device__ __constant__ int ATT_DY[29] = {
    -3, -2, -2, -2, -2, -2, -1, -1, -1, -1, -1, 0, 0, 0, 0,
    0, 0, 0, 1, 1, 1, 1, 1, 2, 2, 2, 2, 2, 3};
__device__ __constant__ int ATT_DX[29] = {
    0, -2, -1, 0, 1, 2, -2, -1, 0, 1, 2, -3, -2, -1, 0,
    1, 2, 3, -2, -1, 0, 1, 2, -2, -1, 0, 1, 2, 0};

__global__ __launch_bounds__(128) void attn_tile_kernel(
    const f16* __restrict__ qf, const f16* __restrict__ kvf,
    f16* __restrict__ ao)
{
    __shared__ f16 ks[196][66];   // odd word stride (33) -> <=3-way banks
    __shared__ f16 vs[196][66];
    const int tile = blockIdx.x, hp = blockIdx.y, b = blockIdx.z;
    const int ty0 = (tile / 6) * 8, tx0 = (tile - (tile / 6) * 6) * 8;
    const int tid = threadIdx.x;

    // stage K/V neighborhood (invalid rows zeroed: stale LDS could be Inf/NaN)
    for (int idx = tid; idx < 196 * 16; idx += 128) {
        const int r = idx >> 4, seg = idx & 15;
        const int gy = ty0 - 3 + r / 14, gx = tx0 - 3 + (r - (r / 14) * 14);
        uint4 val = {0u, 0u, 0u, 0u};
        if ((unsigned)gy < HS && (unsigned)gx < HS) {
            const size_t rowb = ((size_t)b * NN + gy * HS + gx) * 512;
            const int ch = (seg < 8) ? (hp * 64 + seg * 8)
                                     : (256 + hp * 64 + (seg - 8) * 8);
            val = *(const uint4*)&kvf[rowb + ch];
        }
        f16* dstp = (seg < 8) ? &ks[r][(seg & 7) * 8] : &vs[r][(seg & 7) * 8];
        ((unsigned int*)dstp)[0] = val.x;   // b32 writes: 66-stride rows are
        ((unsigned int*)dstp)[1] = val.y;   // not 16B-aligned for odd r
        ((unsigned int*)dstp)[2] = val.z;
        ((unsigned int*)dstp)[3] = val.w;
    }
    __syncthreads();

    const int q = tid & 63, hh = tid >> 6;
    const int qy = q >> 3, qx = q & 7;
    const size_t qrow = (size_t)b * NN + (ty0 + qy) * HS + tx0 + qx;
    const f16* qp = qf + qrow * CC + hp * 64 + hh * 32;
    uint4 qa[4];
#pragma unroll
    for (int i = 0; i < 4; ++i) qa[i] = ((const uint4*)qp)[i];
    const h2* q2 = (const h2*)qa;

    // pass 1: scores
    float s[29];
#pragma unroll
    for (int n = 0; n < 29; ++n) {
        const int dy = ATT_DY[n], dx = ATT_DX[n];
        const int r = (qy + 3 + dy) * 14 + qx + 3 + dx;
        const bool valid = (unsigned)(ty0 + qy + dy) < HS &&
                           (unsigned)(tx0 + qx + dx) < HS;
        float a = 0.0f;
        const h2* kp = (const h2*)&ks[r][hh * 32];
#pragma unroll
        for (int i = 0; i < 16; ++i)
            a = __builtin_amdgcn_fdot2(q2[i], kp[i], a, false);
        s[n] = valid ? a * ATTN_SCALE : -1e30f;
    }
    // pass 2: softmax
    float m = s[0];
#pragma unroll
    for (int n = 1; n < 29; ++n) m = fmaxf(m, s[n]);
    float l = 0.0f;
#pragma unroll
    for (int n = 0; n < 29; ++n) { s[n] = __expf(s[n] - m); l += s[n]; }
    // pass 3: PV (packed f16 fma; p==0 for invalid -> zero contribution)
    h2 a2[16];
#pragma unroll
    for (int i = 0; i < 16; ++i) a2[i] = (h2){(f16)0.f, (f16)0.f};
#pragma unroll
    for (int n = 0; n < 29; ++n) {
        const int dy = ATT_DY[n], dx = ATT_DX[n];
        const int r = (qy + 3 + dy) * 14 + qx + 3 + dx;
        const f16 pn = (f16)s[n];
        const h2 ph = (h2){pn, pn};
        const h2* vp = (const h2*)&vs[r][hh * 32];
#pragma unroll
        for (int i = 0; i < 16; ++i) a2[i] += ph * vp[i];
    }
    const float inv = 1.0f / l;
    uint4 ov[4];
    f16* oh = (f16*)ov;
#pragma unroll
    for (int i = 0; i < 16; ++i) {
        oh[2 * i]     = (f16)((float)a2[i][0] * inv);
        oh[2 * i + 1] = (f16)((float)a2[i][1] * inv);
    }
    uint4* dst = (uint4*)(ao + qrow * CC + hp * 64 + hh * 32);
#pragma unroll
    for (int i = 0; i < 4; ++i) dst[i] = ov[i];
}

extern "C" void kernel_launch(void* const* d_in, const int* in_sizes, int n_in,
                              void* d_out, int out_size, void* d_ws, size_t ws_size,
                              hipStream_t stream) {
    const float* x    = (const float*)d_in[0];
    const float* x_kv = (const float*)d_in[1];
    const float* Wq   = (const float*)d_in[2];
    const float* bq   = (const float*)d_in[3];
    const float* Wk   = (const float*)d_in[4];
    const float* bk   = (const float*)d_in[5];
    const float* Wv   = (const float*)d_in[6];
    const float* bv   = (const float*)d_in[7];
    const float* Wp   = (const float*)d_in[8];
    const float* bp   = (const float*)d_in[9];
    const float* g1   = (const float*)d_in[10];
    const float* b1   = (const float*)d_in[11];
    const float* g2   = (const float*)d_in[12];
    const float* b2   = (const float*)d_in[13];
    const float* W1   = (const float*)d_in[14];
    const float* bm1  = (const float*)d_in[15];
    const float* W2   = (const float*)d_in[16];
    const float* bm2  = (const float*)d_in[17];
    float* outp = (float*)d_out;   // fp32 output (verified)

    // ws layout (f16 element offsets). Overlays (stream-ordered lifetimes):
    //   ao over hq (hq dead after q-GEMM); x1 (fp32) over hkv+qf (dead after
    //   kv-GEMM/attn); m2 over kvf 1st half (dead after attn); per-batch hid
    //   over kvf 2nd half. Fused hid appended (+18.9 MB) if ws allows.
    f16* wsh = (f16*)d_ws;
    f16* WqT  = wsh;                         // 65536
    f16* WkvT = wsh + 65536;                 // 131072
    f16* WpT  = wsh + 196608;                // 65536
    f16* W1T  = wsh + 262144;                // 262144
    f16* W2T  = wsh + 524288;                // 262144
    f16* hq   = wsh + 786432;                // 2359296
    f16* hkv  = wsh + 3145728;               // 2359296
    f16* qf   = wsh + 5505024;               // 2359296
    f16* kvf  = wsh + 7864320;               // 4718592
    f16* ao   = hq;
    float* x1 = (float*)(wsh + 3145728);     // 2359296 floats == hkv+qf bytes
    f16* m2   = kvf;                         // first 2359296 of kvf
    f16* hidF = wsh + 12582912;              // fused: 9437184 -> end 22020096
    f16* hidB = wsh + 10223616;              // per-batch: 2359296 (kvf 2nd half)
    const bool fused = ws_size >= (size_t)22020096 * sizeof(f16);

    // 0. weight transpose+cast (once per call)
    prep_kernel<<<768, 256, 0, stream>>>(Wq, Wk, Wv, Wp, W1, W2,
                                         WqT, WkvT, WpT, W1T, W2T);
    // 1. LN of x and x_kv
    ln_dual_kernel<<<2 * BNROWS, 256, 0, stream>>>(x, x_kv, g1, b1, hq, hkv);
    // 2. Q and fused K|V projections
    gemm_f16<false, 0, 0, false><<<dim3(4, 72), 256, 0, stream>>>(
        hq, WqT, bq, nullptr, nullptr, qf, BNROWS, CC, CC);
    gemm_f16<false, 0, 0, true><<<dim3(8, 72), 256, 0, stream>>>(
        hkv, WkvT, bk, bv, nullptr, kvf, BNROWS, 512, CC);
    // 3. attention
    attn_tile_kernel<<<dim3(36, 4, BB), 128, 0, stream>>>(qf, kvf, ao);
    // 4. out-proj + residual x -> x1 (fp32)
    gemm_f16<false, 1, 1, false><<<dim3(4, 72), 256, 0, stream>>>(
        ao, WpT, bp, nullptr, x, x1, BNROWS, CC, CC);
    // 5. LN2 -> m2
    ln_single_kernel<<<BNROWS, 256, 0, stream>>>(x1, g2, b2, m2);
    // 6/7. MLP
    if (fused) {
        gemm_f16<true, 0, 0, false><<<dim3(16, 72), 256, 0, stream>>>(
            m2, W1T, bm1, nullptr, nullptr, hidF, BNROWS, HID, CC);
        gemm_f16<false, 1, 1, false><<<dim3(4, 72), 256, 0, stream>>>(
            hidF, W2T, bm2, nullptr, x1, outp, BNROWS, CC, HID);
    } else {
        for (int b = 0; b < BB; ++b) {
            const size_t off = (size_t)b * NN * CC;
            gemm_f16<true, 0, 0, false><<<dim3(16, 18), 256, 0, stream>>>(
                m2 + off, W1T, bm1, nullptr, nullptr, hidB, NN, HID, CC);
            gemm_f16<false, 1, 1, false><<<dim3(4, 18), 256, 0, stream>>>(
                hidB, W2T, bm2, nullptr, x1 + off, outp + off, NN, CC, HID);
        }
    }
    (void)in_sizes; (void)n_in; (void)out_size;
}

// Round 8
// 200.084 us; speedup vs baseline: 9.3123x; 1.0531x over previous
//
#include <hip/hip_runtime.h>
#include <hip/hip_fp16.h>
#include <math.h>

#define BB 4
#define NN 2304
#define CC 256
#define HS 48
#define HID 1024
#define BNROWS (BB * NN)                 // 9216
#define ATTN_SCALE 0.17677669529663687f  // 32^-0.5

typedef _Float16 f16;
typedef __attribute__((ext_vector_type(2))) _Float16 h2;
typedef __attribute__((ext_vector_type(8))) _Float16 h8;
typedef __attribute__((ext_vector_type(4))) float f4;

static __device__ __forceinline__ float wave_sum64(float v) {
    v += __shfl_xor(v, 32, 64);
    v += __shfl_xor(v, 16, 64);
    v += __shfl_xor(v, 8, 64);
    v += __shfl_xor(v, 4, 64);
    v += __shfl_xor(v, 2, 64);
    v += __shfl_xor(v, 1, 64);
    return v;
}

// ---------------- weight prep ----------------
// fp32 [K][N] -> f16 [N][K] transposed; Wq/Wk/Wv fused into WqkvT [768][256];
// block 768 builds the fused 768-entry QKV bias.
__global__ __launch_bounds__(256) void prep_kernel(
    const float* __restrict__ Wq, const float* __restrict__ Wk,
    const float* __restrict__ Wv, const float* __restrict__ Wp,
    const float* __restrict__ W1, const float* __restrict__ W2,
    const float* __restrict__ bq, const float* __restrict__ bk,
    const float* __restrict__ bv,
    f16* __restrict__ WqkvT, f16* __restrict__ WpT,
    f16* __restrict__ W1T, f16* __restrict__ W2T, float* __restrict__ bqkv)
{
    int bx = blockIdx.x;
    if (bx == 768) {  // fused QKV bias
        const int t = threadIdx.x;
        bqkv[t]       = bq[t];
        bqkv[t + 256] = bk[t];
        bqkv[t + 512] = bv[t];
        return;
    }
    __shared__ float tt[32][33];
    const float* src; f16* dst; int K, N;
    if (bx < 64)        { src = Wq; dst = WqkvT;             K = 256;  N = 256; }
    else if (bx < 128)  { src = Wk; dst = WqkvT + 65536;     K = 256;  N = 256;  bx -= 64; }
    else if (bx < 192)  { src = Wv; dst = WqkvT + 131072;    K = 256;  N = 256;  bx -= 128; }
    else if (bx < 256)  { src = Wp; dst = WpT;               K = 256;  N = 256;  bx -= 192; }
    else if (bx < 512)  { src = W1; dst = W1T;               K = 256;  N = 1024; bx -= 256; }
    else                { src = W2; dst = W2T;               K = 1024; N = 256;  bx -= 512; }
    const int tN = N >> 5;
    const int kt = bx / tN, nt = bx - kt * tN;
    const int rr = threadIdx.x >> 5, cc = threadIdx.x & 31;
#pragma unroll
    for (int j = 0; j < 4; ++j)
        tt[rr + 8 * j][cc] = src[(size_t)(kt * 32 + rr + 8 * j) * N + nt * 32 + cc];
    __syncthreads();
#pragma unroll
    for (int j = 0; j < 4; ++j)
        dst[(size_t)(nt * 32 + rr + 8 * j) * K + kt * 32 + cc] = (f16)tt[cc][rr + 8 * j];
}

// ---------------- LayerNorm, one wave per row ----------------
// LN1: fp32 src (x | x_kv selected by row), f16 dst.
__global__ __launch_bounds__(256) void ln1_kernel(
    const float* __restrict__ x, const float* __restrict__ xkv,
    const float* __restrict__ g, const float* __restrict__ be,
    f16* __restrict__ hq, f16* __restrict__ hkv)
{
    const int r = blockIdx.x * 4 + (threadIdx.x >> 6);  // 0..2*BNROWS-1
    const int lane = threadIdx.x & 63;
    const float* src; f16* dst;
    if (r < BNROWS) { src = x + (size_t)r * CC;             dst = hq + (size_t)r * CC; }
    else { src = xkv + (size_t)(r - BNROWS) * CC; dst = hkv + (size_t)(r - BNROWS) * CC; }
    const float4 v = ((const float4*)src)[lane];
    const float mu = wave_sum64(v.x + v.y + v.z + v.w) * (1.0f / CC);
    const float d0 = v.x - mu, d1 = v.y - mu, d2 = v.z - mu, d3 = v.w - mu;
    const float var = wave_sum64(d0 * d0 + d1 * d1 + d2 * d2 + d3 * d3) * (1.0f / CC);
    const float rs = rsqrtf(var + 1e-6f);
    const float4 g4 = ((const float4*)g)[lane];
    const float4 b4 = ((const float4*)be)[lane];
    h2 o01 = (h2){(f16)(d0 * rs * g4.x + b4.x), (f16)(d1 * rs * g4.y + b4.y)};
    h2 o23 = (h2){(f16)(d2 * rs * g4.z + b4.z), (f16)(d3 * rs * g4.w + b4.w)};
    ((h2*)dst)[lane * 2] = o01;
    ((h2*)dst)[lane * 2 + 1] = o23;
}

// LN2: f16 src, f16 dst.
__global__ __launch_bounds__(256) void ln2_kernel(
    const f16* __restrict__ x1, const float* __restrict__ g,
    const float* __restrict__ be, f16* __restrict__ m2)
{
    const int r = blockIdx.x * 4 + (threadIdx.x >> 6);
    const int lane = threadIdx.x & 63;
    const f16* src = x1 + (size_t)r * CC;
    const h2 a01 = ((const h2*)src)[lane * 2];
    const h2 a23 = ((const h2*)src)[lane * 2 + 1];
    const float v0 = (float)a01[0], v1 = (float)a01[1];
    const float v2 = (float)a23[0], v3 = (float)a23[1];
    const float mu = wave_sum64(v0 + v1 + v2 + v3) * (1.0f / CC);
    const float d0 = v0 - mu, d1 = v1 - mu, d2 = v2 - mu, d3 = v3 - mu;
    const float var = wave_sum64(d0 * d0 + d1 * d1 + d2 * d2 + d3 * d3) * (1.0f / CC);
    const float rs = rsqrtf(var + 1e-6f);
    const float4 g4 = ((const float4*)g)[lane];
    const float4 b4 = ((const float4*)be)[lane];
    f16* dst = m2 + (size_t)r * CC;
    h2 o01 = (h2){(f16)(d0 * rs * g4.x + b4.x), (f16)(d1 * rs * g4.y + b4.y)};
    h2 o23 = (h2){(f16)(d2 * rs * g4.z + b4.z), (f16)(d3 * rs * g4.w + b4.w)};
    ((h2*)dst)[lane * 2] = o01;
    ((h2*)dst)[lane * 2 + 1] = o23;
}

// ---------------- MFMA f16 GEMM, 64x64 tile, BK=64 ----------------
// A f16 [M][K]; Bt f16 [N][K] pre-transposed. 4 waves, each owns a 64x16
// n-strip: 2(kh) x 4(mt) MFMA 16x16x32 per K-iter.
// QKV: N=768; n<256 -> A=Aq out=qf[.,256]; n>=256 -> A=Akv out=kvf[.,512].
// RESID: 0 none, 1 fp32, 2 f16. OUTF32: fp32 store.
template <bool GELU, int RESID, bool OUTF32, bool QKV>
__global__ __launch_bounds__(256) void gemm64(
    const f16* __restrict__ Aq, const f16* __restrict__ Akv,
    const f16* __restrict__ Bt, const float* __restrict__ bias,
    const void* __restrict__ resid, void* __restrict__ out1,
    void* __restrict__ outkv, int M, int N, int K)
{
    __shared__ f16 As[64][72];   // stride 144 B: 16B-aligned, odd 16B count
    __shared__ f16 Bs[64][72];
    const int tid = threadIdx.x;
    const int wid = tid >> 6, lane = tid & 63;
    const int ln15 = lane & 15, quad = lane >> 4;
    const int m0 = blockIdx.y * 64;
    const int n0 = blockIdx.x * 64;
    const bool kv = QKV && (n0 >= 256);
    const f16* Ap = (QKV && kv) ? Akv : Aq;

    const int sr = tid >> 2;             // 0..63
    const int sk = (tid & 3) << 4;       // 0,16,32,48

    f4 acc[4];
#pragma unroll
    for (int i = 0; i < 4; ++i) acc[i] = (f4){0.f, 0.f, 0.f, 0.f};

    for (int k0 = 0; k0 < K; k0 += 64) {
        const f16* ag = Ap + (size_t)(m0 + sr) * K + k0 + sk;
        const f16* bg = Bt + (size_t)(n0 + sr) * K + k0 + sk;
        *(uint4*)&As[sr][sk]     = *(const uint4*)ag;
        *(uint4*)&As[sr][sk + 8] = *(const uint4*)(ag + 8);
        *(uint4*)&Bs[sr][sk]     = *(const uint4*)bg;
        *(uint4*)&Bs[sr][sk + 8] = *(const uint4*)(bg + 8);
        __syncthreads();
#pragma unroll
        for (int kh = 0; kh < 2; ++kh) {
            const h8 bF = *(const h8*)&Bs[wid * 16 + ln15][kh * 32 + quad * 8];
#pragma unroll
            for (int mt = 0; mt < 4; ++mt) {
                const h8 aF = *(const h8*)&As[mt * 16 + ln15][kh * 32 + quad * 8];
                acc[mt] = __builtin_amdgcn_mfma_f32_16x16x32_f16(aF, bF, acc[mt], 0, 0, 0);
            }
        }
        __syncthreads();
    }

    const int gn = n0 + wid * 16 + ln15;
    const float bs = bias[gn];
#pragma unroll
    for (int mt = 0; mt < 4; ++mt) {
#pragma unroll
        for (int r = 0; r < 4; ++r) {
            const int gm = m0 + mt * 16 + quad * 4 + r;
            float v = acc[mt][r] + bs;
            if (GELU) v = 0.5f * v * (1.0f + erff(v * 0.70710678118654752f));
            if (RESID == 1) v += ((const float*)resid)[(size_t)gm * N + gn];
            if (RESID == 2) v += (float)((const f16*)resid)[(size_t)gm * N + gn];
            if (QKV) {
                if (kv) ((f16*)outkv)[(size_t)gm * 512 + (gn - 256)] = (f16)v;
                else    ((f16*)out1)[(size_t)gm * 256 + gn] = (f16)v;
            } else if (OUTF32) {
                ((float*)out1)[(size_t)gm * N + gn] = v;
            } else {
                ((f16*)out1)[(size_t)gm * N + gn] = (f16)v;
            }
        }
    }
}

// ---------------- tiled sparse spatial attention ----------------
// Block = (8x8 query tile, head-pair, batch); 128 threads = (64 q) x (2 heads).
// K/V neighborhood (14x14 rows x 64 ch) in LDS f16. exp(-1e9-m)==0 in fp32 so
// only in-radius keys contribute (== reference softmax).
__device__ __constant__ int ATT_DY[29] = {
    -3, -2, -2, -2, -2, -2, -1, -1, -1, -1, -1, 0, 0, 0, 0,
    0, 0, 0, 1, 1, 1, 1, 1, 2, 2, 2, 2, 2, 3};
__device__ __constant__ int ATT_DX[29] = {
    0, -2, -1, 0, 1, 2, -2, -1, 0, 1, 2, -3, -2, -1, 0,
    1, 2, 3, -2, -1, 0, 1, 2, -2, -1, 0, 1, 2, 0};

__global__ __launch_bounds__(128) void attn_tile_kernel(
    const f16* __restrict__ qf, const f16* __restrict__ kvf,
    f16* __restrict__ ao)
{
    __shared__ f16 ks[196][66];
    __shared__ f16 vs[196][66];
    const int tile = blockIdx.x, hp = blockIdx.y, b = blockIdx.z;
    const int ty0 = (tile / 6) * 8, tx0 = (tile - (tile / 6) * 6) * 8;
    const int tid = threadIdx.x;

    for (int idx = tid; idx < 196 * 16; idx += 128) {
        const int r = idx >> 4, seg = idx & 15;
        const int gy = ty0 - 3 + r / 14, gx = tx0 - 3 + (r - (r / 14) * 14);
        uint4 val = {0u, 0u, 0u, 0u};
        if ((unsigned)gy < HS && (unsigned)gx < HS) {
            const size_t rowb = ((size_t)b * NN + gy * HS + gx) * 512;
            const int ch = (seg < 8) ? (hp * 64 + seg * 8)
                                     : (256 + hp * 64 + (seg - 8) * 8);
            val = *(const uint4*)&kvf[rowb + ch];
        }
        f16* dstp = (seg < 8) ? &ks[r][(seg & 7) * 8] : &vs[r][(seg & 7) * 8];
        ((unsigned int*)dstp)[0] = val.x;
        ((unsigned int*)dstp)[1] = val.y;
        ((unsigned int*)dstp)[2] = val.z;
        ((unsigned int*)dstp)[3] = val.w;
    }
    __syncthreads();

    const int q = tid & 63, hh = tid >> 6;
    const int qy = q >> 3, qx = q & 7;
    const size_t qrow = (size_t)b * NN + (ty0 + qy) * HS + tx0 + qx;
    const f16* qp = qf + qrow * CC + hp * 64 + hh * 32;
    uint4 qa[4];
#pragma unroll
    for (int i = 0; i < 4; ++i) qa[i] = ((const uint4*)qp)[i];
    const h2* q2 = (const h2*)qa;

    float s[29];
#pragma unroll
    for (int n = 0; n < 29; ++n) {
        const int dy = ATT_DY[n], dx = ATT_DX[n];
        const int r = (qy + 3 + dy) * 14 + qx + 3 + dx;
        const bool valid = (unsigned)(ty0 + qy + dy) < HS &&
                           (unsigned)(tx0 + qx + dx) < HS;
        float a = 0.0f;
        const h2* kp = (const h2*)&ks[r][hh * 32];
#pragma unroll
        for (int i = 0; i < 16; ++i)
            a = __builtin_amdgcn_fdot2(q2[i], kp[i], a, false);
        s[n] = valid ? a * ATTN_SCALE : -1e30f;
    }
    float m = s[0];
#pragma unroll
    for (int n = 1; n < 29; ++n) m = fmaxf(m, s[n]);
    float l = 0.0f;
#pragma unroll
    for (int n = 0; n < 29; ++n) { s[n] = __expf(s[n] - m); l += s[n]; }
    h2 a2[16];
#pragma unroll
    for (int i = 0; i < 16; ++i) a2[i] = (h2){(f16)0.f, (f16)0.f};
#pragma unroll
    for (int n = 0; n < 29; ++n) {
        const int dy = ATT_DY[n], dx = ATT_DX[n];
        const int r = (qy + 3 + dy) * 14 + qx + 3 + dx;
        const f16 pn = (f16)s[n];
        const h2 ph = (h2){pn, pn};
        const h2* vp = (const h2*)&vs[r][hh * 32];
#pragma unroll
        for (int i = 0; i < 16; ++i) a2[i] += ph * vp[i];
    }
    const float inv = 1.0f / l;
    uint4 ov[4];
    f16* oh = (f16*)ov;
#pragma unroll
    for (int i = 0; i < 16; ++i) {
        oh[2 * i]     = (f16)((float)a2[i][0] * inv);
        oh[2 * i + 1] = (f16)((float)a2[i][1] * inv);
    }
    uint4* dst = (uint4*)(ao + qrow * CC + hp * 64 + hh * 32);
#pragma unroll
    for (int i = 0; i < 4; ++i) dst[i] = ov[i];
}

extern "C" void kernel_launch(void* const* d_in, const int* in_sizes, int n_in,
                              void* d_out, int out_size, void* d_ws, size_t ws_size,
                              hipStream_t stream) {
    const float* x    = (const float*)d_in[0];
    const float* x_kv = (const float*)d_in[1];
    const float* Wq   = (const float*)d_in[2];
    const float* bq   = (const float*)d_in[3];
    const float* Wk   = (const float*)d_in[4];
    const float* bk   = (const float*)d_in[5];
    const float* Wv   = (const float*)d_in[6];
    const float* bv   = (const float*)d_in[7];
    const float* Wp   = (const float*)d_in[8];
    const float* bp   = (const float*)d_in[9];
    const float* g1   = (const float*)d_in[10];
    const float* b1   = (const float*)d_in[11];
    const float* g2   = (const float*)d_in[12];
    const float* b2   = (const float*)d_in[13];
    const float* W1   = (const float*)d_in[14];
    const float* bm1  = (const float*)d_in[15];
    const float* W2   = (const float*)d_in[16];
    const float* bm2  = (const float*)d_in[17];
    float* outp = (float*)d_out;   // fp32 output (verified)

    // ws layout (f16 element offsets). Overlays by stream-ordered lifetime:
    //   ao over hq (dead after qkv); x1(f16) over hkv (dead after qkv);
    //   m2 over qf (dead after attn); hid over kvf.. (dead after attn).
    f16* wsh = (f16*)d_ws;
    f16* WqkvT = wsh;                    // 196608
    f16* WpT   = wsh + 196608;           // 65536
    f16* W1T   = wsh + 262144;           // 262144
    f16* W2T   = wsh + 524288;           // 262144
    float* bqkv = (float*)(wsh + 786432);  // 768 fp32 = 1536 f16
    f16* hq    = wsh + 787968;           // 2359296
    f16* hkv   = wsh + 3147264;          // 2359296
    f16* qf    = wsh + 5506560;          // 2359296
    f16* kvf   = wsh + 7865856;          // 4718592 (end 12584448)
    f16* ao    = hq;
    f16* x1    = hkv;
    f16* m2    = qf;
    f16* hidF  = kvf;                    // 9437184 -> end 17303040 (34.6 MB)
    const bool fused = ws_size >= (size_t)17303040 * sizeof(f16);

    // 0. weight transpose/cast + fused qkv bias
    prep_kernel<<<769, 256, 0, stream>>>(Wq, Wk, Wv, Wp, W1, W2, bq, bk, bv,
                                         WqkvT, WpT, W1T, W2T, bqkv);
    // 1. LN1 (x -> hq, x_kv -> hkv), one wave per row
    ln1_kernel<<<2 * BNROWS / 4, 256, 0, stream>>>(x, x_kv, g1, b1, hq, hkv);
    // 2. fused Q|K|V projection (N = 768)
    gemm64<false, 0, false, true><<<dim3(12, 144), 256, 0, stream>>>(
        hq, hkv, WqkvT, bqkv, nullptr, qf, kvf, BNROWS, 768, CC);
    // 3. attention
    attn_tile_kernel<<<dim3(36, 4, BB), 128, 0, stream>>>(qf, kvf, ao);
    // 4. out-proj + residual x (fp32) -> x1 (f16)
    gemm64<false, 1, false, false><<<dim3(4, 144), 256, 0, stream>>>(
        ao, nullptr, WpT, bp, x, x1, nullptr, BNROWS, CC, CC);
    // 5. LN2 -> m2
    ln2_kernel<<<BNROWS / 4, 256, 0, stream>>>(x1, g2, b2, m2);
    // 6/7. MLP
    if (fused) {
        gemm64<true, 0, false, false><<<dim3(16, 144), 256, 0, stream>>>(
            m2, nullptr, W1T, bm1, nullptr, hidF, nullptr, BNROWS, HID, CC);
        gemm64<false, 2, true, false><<<dim3(4, 144), 256, 0, stream>>>(
            hidF, nullptr, W2T, bm2, x1, outp, nullptr, BNROWS, CC, HID);
    } else {
        for (int b = 0; b < BB; ++b) {
            const size_t off = (size_t)b * NN * CC;
            gemm64<true, 0, false, false><<<dim3(16, 36), 256, 0, stream>>>(
                m2 + off, nullptr, W1T, bm1, nullptr, hidF, nullptr, NN, HID, CC);
            gemm64<false, 2, true, false><<<dim3(4, 36), 256, 0, stream>>>(
                hidF, nullptr, W2T, bm2, x1 + off, outp + off, nullptr, NN, CC, HID);
        }
    }
    (void)in_sizes; (void)n_in; (void)out_size;
}

// Round 10
// 196.934 us; speedup vs baseline: 9.4612x; 1.0160x over previous
//
#include <hip/hip_runtime.h>
#include <hip/hip_fp16.h>
#include <math.h>

#define BB 4
#define NN 2304
#define CC 256
#define HS 48
#define HID 1024
#define BNROWS (BB * NN)                 // 9216
#define ATTN_SCALE 0.17677669529663687f  // 32^-0.5

typedef _Float16 f16;
typedef __attribute__((ext_vector_type(2))) _Float16 h2;
typedef __attribute__((ext_vector_type(8))) _Float16 h8;
typedef __attribute__((ext_vector_type(4))) float f4;

#define GLLS16(g, l)                                                        \
    __builtin_amdgcn_global_load_lds(                                       \
        (const __attribute__((address_space(1))) unsigned int*)(g),         \
        (__attribute__((address_space(3))) unsigned int*)(l), 16, 0, 0)

// Explicit waits: global_load_lds -> ds_read dependency is NOT tracked by
// the compiler (no barrier in the K-loop). Memory clobber pins ordering.
#define WAIT_VM0()   asm volatile("s_waitcnt vmcnt(0)" ::: "memory")
#define WAIT_LGKM0() asm volatile("s_waitcnt lgkmcnt(0)" ::: "memory")

static __device__ __forceinline__ float wave_sum64(float v) {
    v += __shfl_xor(v, 32, 64);
    v += __shfl_xor(v, 16, 64);
    v += __shfl_xor(v, 8, 64);
    v += __shfl_xor(v, 4, 64);
    v += __shfl_xor(v, 2, 64);
    v += __shfl_xor(v, 1, 64);
    return v;
}

// ---------------- weight prep ----------------
__global__ __launch_bounds__(256) void prep_kernel(
    const float* __restrict__ Wq, const float* __restrict__ Wk,
    const float* __restrict__ Wv, const float* __restrict__ Wp,
    const float* __restrict__ W1, const float* __restrict__ W2,
    const float* __restrict__ bq, const float* __restrict__ bk,
    const float* __restrict__ bv,
    f16* __restrict__ WqkvT, f16* __restrict__ WpT,
    f16* __restrict__ W1T, f16* __restrict__ W2T, float* __restrict__ bqkv)
{
    int bx = blockIdx.x;
    if (bx == 768) {
        const int t = threadIdx.x;
        bqkv[t]       = bq[t];
        bqkv[t + 256] = bk[t];
        bqkv[t + 512] = bv[t];
        return;
    }
    __shared__ float tt[32][33];
    const float* src; f16* dst; int K, N;
    if (bx < 64)        { src = Wq; dst = WqkvT;             K = 256;  N = 256; }
    else if (bx < 128)  { src = Wk; dst = WqkvT + 65536;     K = 256;  N = 256;  bx -= 64; }
    else if (bx < 192)  { src = Wv; dst = WqkvT + 131072;    K = 256;  N = 256;  bx -= 128; }
    else if (bx < 256)  { src = Wp; dst = WpT;               K = 256;  N = 256;  bx -= 192; }
    else if (bx < 512)  { src = W1; dst = W1T;               K = 256;  N = 1024; bx -= 256; }
    else                { src = W2; dst = W2T;               K = 1024; N = 256;  bx -= 512; }
    const int tN = N >> 5;
    const int kt = bx / tN, nt = bx - kt * tN;
    const int rr = threadIdx.x >> 5, cc = threadIdx.x & 31;
#pragma unroll
    for (int j = 0; j < 4; ++j)
        tt[rr + 8 * j][cc] = src[(size_t)(kt * 32 + rr + 8 * j) * N + nt * 32 + cc];
    __syncthreads();
#pragma unroll
    for (int j = 0; j < 4; ++j)
        dst[(size_t)(nt * 32 + rr + 8 * j) * K + kt * 32 + cc] = (f16)tt[cc][rr + 8 * j];
}

// ---------------- LayerNorm, one wave per row ----------------
__global__ __launch_bounds__(256) void ln1_kernel(
    const float* __restrict__ x, const float* __restrict__ xkv,
    const float* __restrict__ g, const float* __restrict__ be,
    f16* __restrict__ hq, f16* __restrict__ hkv)
{
    const int r = blockIdx.x * 4 + (threadIdx.x >> 6);  // 0..2*BNROWS-1
    const int lane = threadIdx.x & 63;
    const float* src; f16* dst;
    if (r < BNROWS) { src = x + (size_t)r * CC;             dst = hq + (size_t)r * CC; }
    else { src = xkv + (size_t)(r - BNROWS) * CC; dst = hkv + (size_t)(r - BNROWS) * CC; }
    const float4 v = ((const float4*)src)[lane];
    const float mu = wave_sum64(v.x + v.y + v.z + v.w) * (1.0f / CC);
    const float d0 = v.x - mu, d1 = v.y - mu, d2 = v.z - mu, d3 = v.w - mu;
    const float var = wave_sum64(d0 * d0 + d1 * d1 + d2 * d2 + d3 * d3) * (1.0f / CC);
    const float rs = rsqrtf(var + 1e-6f);
    const float4 g4 = ((const float4*)g)[lane];
    const float4 b4 = ((const float4*)be)[lane];
    h2 o01 = (h2){(f16)(d0 * rs * g4.x + b4.x), (f16)(d1 * rs * g4.y + b4.y)};
    h2 o23 = (h2){(f16)(d2 * rs * g4.z + b4.z), (f16)(d3 * rs * g4.w + b4.w)};
    ((h2*)dst)[lane * 2] = o01;
    ((h2*)dst)[lane * 2 + 1] = o23;
}

__global__ __launch_bounds__(256) void ln2_kernel(
    const f16* __restrict__ x1, const float* __restrict__ g,
    const float* __restrict__ be, f16* __restrict__ m2)
{
    const int r = blockIdx.x * 4 + (threadIdx.x >> 6);
    const int lane = threadIdx.x & 63;
    const f16* src = x1 + (size_t)r * CC;
    const h2 a01 = ((const h2*)src)[lane * 2];
    const h2 a23 = ((const h2*)src)[lane * 2 + 1];
    const float v0 = (float)a01[0], v1 = (float)a01[1];
    const float v2 = (float)a23[0], v3 = (float)a23[1];
    const float mu = wave_sum64(v0 + v1 + v2 + v3) * (1.0f / CC);
    const float d0 = v0 - mu, d1 = v1 - mu, d2 = v2 - mu, d3 = v3 - mu;
    const float var = wave_sum64(d0 * d0 + d1 * d1 + d2 * d2 + d3 * d3) * (1.0f / CC);
    const float rs = rsqrtf(var + 1e-6f);
    const float4 g4 = ((const float4*)g)[lane];
    const float4 b4 = ((const float4*)be)[lane];
    f16* dst = m2 + (size_t)r * CC;
    h2 o01 = (h2){(f16)(d0 * rs * g4.x + b4.x), (f16)(d1 * rs * g4.y + b4.y)};
    h2 o23 = (h2){(f16)(d2 * rs * g4.z + b4.z), (f16)(d3 * rs * g4.w + b4.w)};
    ((h2*)dst)[lane * 2] = o01;
    ((h2*)dst)[lane * 2 + 1] = o23;
}

// ---------------- wave-autonomous MFMA GEMM ----------------
// Each wave owns a TM x 64 tile: private LDS A/B staged with
// global_load_lds (width 16), NO barriers in the K-loop; explicit
// vmcnt(0)/lgkmcnt(0) waits enforce the DMA->ds_read->DMA ordering.
// LDS chunk swizzle: tile (row r, k-chunk q) lives at chunk r*4+((q+(r>>1))&3)
// -> frag ds_read_b128 conflicts drop to 2-way (free).
template <int TM, bool GELU, int RESID, bool OUTF32, bool QKV>
__global__ __launch_bounds__(256, 4) void gemm_wave(
    const f16* __restrict__ Aq, const f16* __restrict__ Akv,
    const f16* __restrict__ Bt, const float* __restrict__ bias,
    const void* __restrict__ resid, void* __restrict__ out1,
    void* __restrict__ outkv, int M, int N, int K)
{
    constexpr int AT = TM / 16;            // a-frags per wave
    constexpr int AELEM = TM * 32;         // A tile elems
    __shared__ f16 lds[4 * (AELEM + 2048)];
    const int tid = threadIdx.x;
    const int wid = tid >> 6, lane = tid & 63;
    const int ln15 = lane & 15, quad = lane >> 4;
    f16* Al = lds + wid * (AELEM + 2048);
    f16* Bl = Al + AELEM;
    const int n0 = blockIdx.x * 64;
    const int m0 = (blockIdx.y * 4 + wid) * TM;
    const f16* Ap = QKV ? (n0 < 256 ? Aq : Akv) : Aq;

    // glls per-lane source offsets (element units, k0 added per iter)
    const int jr = lane >> 2, js = lane & 3;
    size_t ga[AT], gb[4];
#pragma unroll
    for (int i = 0; i < AT; ++i) {
        const int r = i * 16 + jr;
        const int q = (js - (r >> 1)) & 3;
        ga[i] = (size_t)(m0 + r) * K + q * 8;
    }
#pragma unroll
    for (int i = 0; i < 4; ++i) {
        const int r = i * 16 + jr;
        const int q = (js - (r >> 1)) & 3;
        gb[i] = (size_t)(n0 + r) * K + q * 8;
    }
    // frag LDS byte offsets (swizzled), constant across K
    int aoff[AT], boff[4];
#pragma unroll
    for (int mt = 0; mt < AT; ++mt) {
        const int r = mt * 16 + ln15;
        aoff[mt] = (r * 4 + ((quad + (r >> 1)) & 3)) * 16;
    }
#pragma unroll
    for (int nt = 0; nt < 4; ++nt) {
        const int r = nt * 16 + ln15;
        boff[nt] = (r * 4 + ((quad + (r >> 1)) & 3)) * 16;
    }

    f4 acc[AT][4];
#pragma unroll
    for (int i = 0; i < AT; ++i)
#pragma unroll
        for (int j = 0; j < 4; ++j) acc[i][j] = (f4){0.f, 0.f, 0.f, 0.f};

    for (int k0 = 0; k0 < K; k0 += 32) {
        if (k0) WAIT_LGKM0();   // prior ds_reads retired before LDS overwrite
#pragma unroll
        for (int i = 0; i < AT; ++i)
            GLLS16(Ap + ga[i] + k0, Al + i * 512);
#pragma unroll
        for (int i = 0; i < 4; ++i)
            GLLS16(Bt + gb[i] + k0, Bl + i * 512);
        WAIT_VM0();             // DMA landed before the fragment reads
        h8 bF[4], aF[AT];
#pragma unroll
        for (int nt = 0; nt < 4; ++nt)
            bF[nt] = *(const h8*)((const char*)Bl + boff[nt]);
#pragma unroll
        for (int mt = 0; mt < AT; ++mt)
            aF[mt] = *(const h8*)((const char*)Al + aoff[mt]);
#pragma unroll
        for (int mt = 0; mt < AT; ++mt)
#pragma unroll
            for (int nt = 0; nt < 4; ++nt)
                acc[mt][nt] = __builtin_amdgcn_mfma_f32_16x16x32_f16(
                    aF[mt], bF[nt], acc[mt][nt], 0, 0, 0);
    }

#pragma unroll
    for (int nt = 0; nt < 4; ++nt) {
        const int gn = n0 + nt * 16 + ln15;
        const float bs = bias[gn];
#pragma unroll
        for (int mt = 0; mt < AT; ++mt) {
#pragma unroll
            for (int r = 0; r < 4; ++r) {
                const int gm = m0 + mt * 16 + quad * 4 + r;
                float v = acc[mt][nt][r] + bs;
                if (GELU) v = 0.5f * v * (1.0f + erff(v * 0.70710678118654752f));
                if (RESID == 1) v += ((const float*)resid)[(size_t)gm * N + gn];
                if (RESID == 2) v += (float)((const f16*)resid)[(size_t)gm * N + gn];
                if (QKV) {
                    if (gn < 256) ((f16*)out1)[(size_t)gm * 256 + gn] = (f16)v;
                    else ((f16*)outkv)[(size_t)gm * 512 + (gn - 256)] = (f16)v;
                } else if (OUTF32) {
                    ((float*)out1)[(size_t)gm * N + gn] = v;
                } else {
                    ((f16*)out1)[(size_t)gm * N + gn] = (f16)v;
                }
            }
        }
    }
}

// ---------------- tiled sparse spatial attention ----------------
// exp(-1e9-m)==0 in fp32 so only in-radius keys contribute (== reference).
__device__ __constant__ int ATT_DY[29] = {
    -3, -2, -2, -2, -2, -2, -1, -1, -1, -1, -1, 0, 0, 0, 0,
    0, 0, 0, 1, 1, 1, 1, 1, 2, 2, 2, 2, 2, 3};
__device__ __constant__ int ATT_DX[29] = {
    0, -2, -1, 0, 1, 2, -2, -1, 0, 1, 2, -3, -2, -1, 0,
    1, 2, 3, -2, -1, 0, 1, 2, -2, -1, 0, 1, 2, 0};

__global__ __launch_bounds__(128) void attn_tile_kernel(
    const f16* __restrict__ qf, const f16* __restrict__ kvf,
    f16* __restrict__ ao)
{
    __shared__ f16 ks[196][66];
    __shared__ f16 vs[196][66];
    const int tile = blockIdx.x, hp = blockIdx.y, b = blockIdx.z;
    const int ty0 = (tile / 6) * 8, tx0 = (tile - (tile / 6) * 6) * 8;
    const int tid = threadIdx.x;

    for (int idx = tid; idx < 196 * 16; idx += 128) {
        const int r = idx >> 4, seg = idx & 15;
        const int gy = ty0 - 3 + r / 14, gx = tx0 - 3 + (r - (r / 14) * 14);
        uint4 val = {0u, 0u, 0u, 0u};
        if ((unsigned)gy < HS && (unsigned)gx < HS) {
            const size_t rowb = ((size_t)b * NN + gy * HS + gx) * 512;
            const int ch = (seg < 8) ? (hp * 64 + seg * 8)
                                     : (256 + hp * 64 + (seg - 8) * 8);
            val = *(const uint4*)&kvf[rowb + ch];
        }
        f16* dstp = (seg < 8) ? &ks[r][(seg & 7) * 8] : &vs[r][(seg & 7) * 8];
        ((unsigned int*)dstp)[0] = val.x;
        ((unsigned int*)dstp)[1] = val.y;
        ((unsigned int*)dstp)[2] = val.z;
        ((unsigned int*)dstp)[3] = val.w;
    }
    __syncthreads();

    const int q = tid & 63, hh = tid >> 6;
    const int qy = q >> 3, qx = q & 7;
    const size_t qrow = (size_t)b * NN + (ty0 + qy) * HS + tx0 + qx;
    const f16* qp = qf + qrow * CC + hp * 64 + hh * 32;
    uint4 qa[4];
#pragma unroll
    for (int i = 0; i < 4; ++i) qa[i] = ((const uint4*)qp)[i];
    const h2* q2 = (const h2*)qa;

    float s[29];
#pragma unroll
    for (int n = 0; n < 29; ++n) {
        const int dy = ATT_DY[n], dx = ATT_DX[n];
        const int r = (qy + 3 + dy) * 14 + qx + 3 + dx;
        const bool valid = (unsigned)(ty0 + qy + dy) < HS &&
                           (unsigned)(tx0 + qx + dx) < HS;
        float a = 0.0f;
        const h2* kp = (const h2*)&ks[r][hh * 32];
#pragma unroll
        for (int i = 0; i < 16; ++i)
            a = __builtin_amdgcn_fdot2(q2[i], kp[i], a, false);
        s[n] = valid ? a * ATTN_SCALE : -1e30f;
    }
    float m = s[0];
#pragma unroll
    for (int n = 1; n < 29; ++n) m = fmaxf(m, s[n]);
    float l = 0.0f;
#pragma unroll
    for (int n = 0; n < 29; ++n) { s[n] = __expf(s[n] - m); l += s[n]; }
    h2 a2[16];
#pragma unroll
    for (int i = 0; i < 16; ++i) a2[i] = (h2){(f16)0.f, (f16)0.f};
#pragma unroll
    for (int n = 0; n < 29; ++n) {
        const int dy = ATT_DY[n], dx = ATT_DX[n];
        const int r = (qy + 3 + dy) * 14 + qx + 3 + dx;
        const f16 pn = (f16)s[n];
        const h2 ph = (h2){pn, pn};
        const h2* vp = (const h2*)&vs[r][hh * 32];
#pragma unroll
        for (int i = 0; i < 16; ++i) a2[i] += ph * vp[i];
    }
    const float inv = 1.0f / l;
    uint4 ov[4];
    f16* oh = (f16*)ov;
#pragma unroll
    for (int i = 0; i < 16; ++i) {
        oh[2 * i]     = (f16)((float)a2[i][0] * inv);
        oh[2 * i + 1] = (f16)((float)a2[i][1] * inv);
    }
    uint4* dst = (uint4*)(ao + qrow * CC + hp * 64 + hh * 32);
#pragma unroll
    for (int i = 0; i < 4; ++i) dst[i] = ov[i];
}

extern "C" void kernel_launch(void* const* d_in, const int* in_sizes, int n_in,
                              void* d_out, int out_size, void* d_ws, size_t ws_size,
                              hipStream_t stream) {
    const float* x    = (const float*)d_in[0];
    const float* x_kv = (const float*)d_in[1];
    const float* Wq   = (const float*)d_in[2];
    const float* bq   = (const float*)d_in[3];
    const float* Wk   = (const float*)d_in[4];
    const float* bk   = (const float*)d_in[5];
    const float* Wv   = (const float*)d_in[6];
    const float* bv   = (const float*)d_in[7];
    const float* Wp   = (const float*)d_in[8];
    const float* bp   = (const float*)d_in[9];
    const float* g1   = (const float*)d_in[10];
    const float* b1   = (const float*)d_in[11];
    const float* g2   = (const float*)d_in[12];
    const float* b2   = (const float*)d_in[13];
    const float* W1   = (const float*)d_in[14];
    const float* bm1  = (const float*)d_in[15];
    const float* W2   = (const float*)d_in[16];
    const float* bm2  = (const float*)d_in[17];
    float* outp = (float*)d_out;   // fp32 output (verified)

    // ws layout (f16 element offsets); overlays by stream-ordered lifetime:
    //   ao over hq (dead after qkv); x1 over hkv (dead after qkv);
    //   m2 over qf (dead after attn); hidF over kvf.. (dead after attn).
    f16* wsh = (f16*)d_ws;
    f16* WqkvT = wsh;                      // 196608
    f16* WpT   = wsh + 196608;             // 65536
    f16* W1T   = wsh + 262144;             // 262144
    f16* W2T   = wsh + 524288;             // 262144
    float* bqkv = (float*)(wsh + 786432);  // 768 fp32
    f16* hq    = wsh + 787968;             // 2359296
    f16* hkv   = wsh + 3147264;            // 2359296
    f16* qf    = wsh + 5506560;            // 2359296
    f16* kvf   = wsh + 7865856;            // 4718592 (end 12584448)
    f16* ao    = hq;
    f16* x1    = hkv;
    f16* m2    = qf;
    f16* hidF  = kvf;                      // 9437184 -> end 17303040 (34.6 MB)
    const bool fused = ws_size >= (size_t)17303040 * sizeof(f16);

    prep_kernel<<<769, 256, 0, stream>>>(Wq, Wk, Wv, Wp, W1, W2, bq, bk, bv,
                                         WqkvT, WpT, W1T, W2T, bqkv);
    ln1_kernel<<<2 * BNROWS / 4, 256, 0, stream>>>(x, x_kv, g1, b1, hq, hkv);
    // fused Q|K|V projection, wave-tiles 64x64: grid (768/64, 144/4)
    gemm_wave<64, false, 0, false, true><<<dim3(12, 36), 256, 0, stream>>>(
        hq, hkv, WqkvT, bqkv, nullptr, qf, kvf, BNROWS, 768, CC);
    attn_tile_kernel<<<dim3(36, 4, BB), 128, 0, stream>>>(qf, kvf, ao);
    // out-proj + fp32 x residual -> x1 (f16); TM=32: grid (4, 288/4)
    gemm_wave<32, false, 1, false, false><<<dim3(4, 72), 256, 0, stream>>>(
        ao, nullptr, WpT, bp, x, x1, nullptr, BNROWS, CC, CC);
    ln2_kernel<<<BNROWS / 4, 256, 0, stream>>>(x1, g2, b2, m2);
    if (fused) {
        gemm_wave<64, true, 0, false, false><<<dim3(16, 36), 256, 0, stream>>>(
            m2, nullptr, W1T, bm1, nullptr, hidF, nullptr, BNROWS, HID, CC);
        gemm_wave<32, false, 2, true, false><<<dim3(4, 72), 256, 0, stream>>>(
            hidF, nullptr, W2T, bm2, x1, outp, nullptr, BNROWS, CC, HID);
    } else {
        for (int b = 0; b < BB; ++b) {
            const size_t off = (size_t)b * NN * CC;
            gemm_wave<64, true, 0, false, false><<<dim3(16, 9), 256, 0, stream>>>(
                m2 + off, nullptr, W1T, bm1, nullptr, hidF, nullptr, NN, HID, CC);
            gemm_wave<32, false, 2, true, false><<<dim3(4, 18), 256, 0, stream>>>(
                hidF, nullptr, W2T, bm2, x1 + off, outp + off, nullptr, NN, CC, HID);
        }
    }
    (void)in_sizes; (void)n_in; (void)out_size;
}